// Round 3
// baseline (144.918 us; speedup 1.0000x reference)
//
#include <hip/hip_runtime.h>

// Problem constants (match reference)
#define HH 256
#define WW 256
#define NPIX (HH * WW)        // 65536
#define NP 512                // points
// ALPHA = -5.0, 1/ALPHA = -0.2

// term2 decomposition: each block = 4 consecutive points x one 32-row slice
#define PPB 4
#define SLICE_ROWS 32
#define NSLICES (HH / SLICE_ROWS)          // 8
#define NPGRP (NP / PPB)                   // 128
#define NB_T2 (NPGRP * NSLICES)            // 1024
#define NB_T1 (NPIX / 256)                 // 256
#define NB_TOTAL (NB_T2 + NB_T1)           // 1280

// ws float layout: [0]=SUM1  [1]=SUM2  [2]=counter(uint)  [3..3+NP)=S[p]
#define WS_SUM1 0
#define WS_SUM2 1
#define WS_CNT  2
#define WS_S    3

__global__ __launch_bounds__(256) void whd_fused_kernel(const float* __restrict__ hm,
                                                        const float* __restrict__ pts,
                                                        float* __restrict__ ws,
                                                        float* __restrict__ out) {
    const int tid = threadIdx.x;
    const int bid = blockIdx.x;
    __shared__ float lred[PPB][4];
    __shared__ float dred[4];
    __shared__ unsigned lastflag;

    if (bid < NB_T2) {
        // ---------------- term 2: soft-min accumulation ----------------
        // dmax, recomputed redundantly per block (cheap): max dist over the
        // integer grid is attained at a corner; d^2 is separable.
        float m = 0.f;
        #pragma unroll
        for (int t = 0; t < 2; ++t) {
            int p = tid + t * 256;
            float py = pts[2 * p], px = pts[2 * p + 1];
            float my = fmaxf(py * py, (255.f - py) * (255.f - py));
            float mx = fmaxf(px * px, (255.f - px) * (255.f - px));
            m = fmaxf(m, my + mx);
        }
        #pragma unroll
        for (int off = 32; off; off >>= 1) m = fmaxf(m, __shfl_down(m, off, 64));
        if ((tid & 63) == 0) dred[tid >> 6] = m;
        __syncthreads();
        const float dmax = sqrtf(fmaxf(fmaxf(dred[0], dred[1]), fmaxf(dred[2], dred[3])));

        const int pgrp  = bid & (NPGRP - 1);
        const int slice = bid >> 7;            // NPGRP = 128
        const int p0    = pgrp * PPB;

        float py[PPB], px[PPB];
        #pragma unroll
        for (int a = 0; a < PPB; ++a) {        // uniform -> SGPR loads
            py[a] = pts[2 * (p0 + a)];
            px[a] = pts[2 * (p0 + a) + 1];
        }

        // this thread owns columns col0..col0+3 of every 4th row -> dx^2 is
        // loop-invariant: precompute 16 registers
        const float col0 = (float)((tid & 63) << 2);
        float dx2[PPB][4];
        #pragma unroll
        for (int a = 0; a < PPB; ++a)
            #pragma unroll
            for (int c = 0; c < 4; ++c) {
                float dx = col0 + (float)c - px[a];
                dx2[a][c] = dx * dx;
            }

        const float4* hm4 = (const float4*)hm;
        const int   gbase   = slice * (SLICE_ROWS * WW / 4) + tid;   // float4 idx
        const float rowbase = (float)(slice * SLICE_ROWS + (tid >> 6));
        float acc[PPB] = {0.f, 0.f, 0.f, 0.f};

        #pragma unroll
        for (int k = 0; k < 8; ++k) {
            float4 h4 = hm4[gbase + k * 256];          // coalesced, L2-hot
            float row = rowbase + (float)(4 * k);
            float dy2[PPB];
            #pragma unroll
            for (int a = 0; a < PPB; ++a) { float dy = row - py[a]; dy2[a] = dy * dy; }
            float hx[4] = {h4.x, h4.y, h4.z, h4.w};
            #pragma unroll
            for (int c = 0; c < 4; ++c) {
                float h = hx[c];
                float cterm = fmaf(-h, dmax, dmax);    // (1-h)*dmax
                #pragma unroll
                for (int a = 0; a < PPB; ++a) {
                    float d  = sqrtf(dy2[a] + dx2[a][c]);
                    float w  = fmaf(h, d, cterm);      // hm*d + (1-hm)*dmax
                    float r  = __builtin_amdgcn_rcpf(w);
                    float r2 = r * r;
                    acc[a]   = fmaf(r2 * r2, r, acc[a]);   // += w^-5
                }
            }
        }
        #pragma unroll
        for (int a = 0; a < PPB; ++a) {
            float v = acc[a];
            #pragma unroll
            for (int off = 32; off; off >>= 1) v += __shfl_down(v, off, 64);
            if ((tid & 63) == 0) lred[a][tid >> 6] = v;
        }
        __syncthreads();
        if (tid < PPB) {
            float s = lred[tid][0] + lred[tid][1] + lred[tid][2] + lred[tid][3];
            atomicAdd(&ws[WS_S + p0 + tid], s);
        }
    } else {
        // ---------------- term 1: heat-weighted min distance ----------------
        const int idx = (bid - NB_T2) * 256 + tid;
        const float fi = (float)(idx >> 8);
        const float fj = (float)(idx & (WW - 1));
        const float4* pts4 = (const float4*)pts;   // uniform idx -> SGPR loads
        float m0 = 3.4e38f, m1 = 3.4e38f, m2 = 3.4e38f, m3 = 3.4e38f;
        #pragma unroll 4
        for (int i = 0; i < NP / 2; i += 4) {
            float4 q0 = pts4[i], q1 = pts4[i + 1], q2 = pts4[i + 2], q3 = pts4[i + 3];
            float dy, dx;
            dy = fi - q0.x; dx = fj - q0.y; m0 = fminf(m0, fmaf(dy, dy, dx * dx));
            dy = fi - q0.z; dx = fj - q0.w; m1 = fminf(m1, fmaf(dy, dy, dx * dx));
            dy = fi - q1.x; dx = fj - q1.y; m2 = fminf(m2, fmaf(dy, dy, dx * dx));
            dy = fi - q1.z; dx = fj - q1.w; m3 = fminf(m3, fmaf(dy, dy, dx * dx));
            dy = fi - q2.x; dx = fj - q2.y; m0 = fminf(m0, fmaf(dy, dy, dx * dx));
            dy = fi - q2.z; dx = fj - q2.w; m1 = fminf(m1, fmaf(dy, dy, dx * dx));
            dy = fi - q3.x; dx = fj - q3.y; m2 = fminf(m2, fmaf(dy, dy, dx * dx));
            dy = fi - q3.z; dx = fj - q3.w; m3 = fminf(m3, fmaf(dy, dy, dx * dx));
        }
        float mind = sqrtf(fminf(fminf(m0, m1), fminf(m2, m3)));
        float h  = hm[idx];
        float v1 = h * mind;
        float v2 = fabsf(h);
        #pragma unroll
        for (int off = 32; off; off >>= 1) {
            v1 += __shfl_down(v1, off, 64);
            v2 += __shfl_down(v2, off, 64);
        }
        if ((tid & 63) == 0) { lred[0][tid >> 6] = v1; lred[1][tid >> 6] = v2; }
        __syncthreads();
        if (tid == 0) atomicAdd(&ws[WS_SUM1], lred[0][0] + lred[0][1] + lred[0][2] + lred[0][3]);
        if (tid == 1) atomicAdd(&ws[WS_SUM2], lred[1][0] + lred[1][1] + lred[1][2] + lred[1][3]);
    }

    // ---------------- completion counter; last block combines ----------------
    __threadfence();                               // release our atomics
    if (tid == 0) {
        unsigned old = atomicAdd((unsigned*)&ws[WS_CNT], 1u);
        lastflag = (old == (unsigned)(NB_TOTAL - 1)) ? 1u : 0u;
    }
    __syncthreads();
    if (lastflag) {
        __threadfence();                           // acquire
        float ssum = 0.f;
        #pragma unroll
        for (int t = 0; t < 2; ++t) {
            int p = tid + t * 256;
            float S = __hip_atomic_load(&ws[WS_S + p], __ATOMIC_RELAXED,
                                        __HIP_MEMORY_SCOPE_AGENT);
            // soft_min[p] = (S/NPIX)^(-1/5) = exp2(-0.2*log2(S/NPIX))
            ssum += exp2f(-0.2f * log2f(S * (1.f / (float)NPIX)));
        }
        #pragma unroll
        for (int off = 32; off; off >>= 1) ssum += __shfl_down(ssum, off, 64);
        if ((tid & 63) == 0) dred[tid >> 6] = ssum;
        __syncthreads();
        if (tid == 0) {
            float s1 = __hip_atomic_load(&ws[WS_SUM1], __ATOMIC_RELAXED,
                                         __HIP_MEMORY_SCOPE_AGENT);
            float s2 = __hip_atomic_load(&ws[WS_SUM2], __ATOMIC_RELAXED,
                                         __HIP_MEMORY_SCOPE_AGENT);
            float tot = dred[0] + dred[1] + dred[2] + dred[3];
            out[0] = s1 / s2 + tot * (1.f / (float)NP);
        }
    }
}

extern "C" void kernel_launch(void* const* d_in, const int* in_sizes, int n_in,
                              void* d_out, int out_size, void* d_ws, size_t ws_size,
                              hipStream_t stream) {
    const float* hm  = (const float*)d_in[0];   // (256,256) f32
    const float* pts = (const float*)d_in[1];   // (512,2)  f32
    float* ws  = (float*)d_ws;
    float* out = (float*)d_out;

    // zero accumulators + counter (ws is re-poisoned to 0xAA before every launch)
    (void)hipMemsetAsync(d_ws, 0, (WS_S + NP) * sizeof(float), stream);

    whd_fused_kernel<<<NB_TOTAL, 256, 0, stream>>>(hm, pts, ws, out);
}